// Round 2
// baseline (276.573 us; speedup 1.0000x reference)
//
#include <hip/hip_runtime.h>
#include <math.h>

#define BATCH 16
#define NCH 20
#define NPOS 27280
#define NTOP 1000
#define KW 16  // ceil(1024/64) words of suppression bits

typedef unsigned long long u64;
typedef unsigned int u32;

// Static device scratch (avoids relying on ws_size). All fully rewritten every call.
__device__ u64 g_key[BATCH * NPOS];                 // 3.5 MB
__device__ unsigned char g_kind[BATCH * NPOS];      // 0.44 MB
__device__ float4 g_box[BATCH * NTOP];              // 0.26 MB
__device__ float g_score[BATCH * NTOP];             // 64 KB
__device__ u64 g_mask[BATCH * NTOP * KW];           // 2 MB

// ---------------- K1: per-position score (sigmoid of max logit) + argmax ----------------
__global__ __launch_bounds__(256) void k1_score(
    const float* __restrict__ c3, const float* __restrict__ c4,
    const float* __restrict__ c5, const float* __restrict__ c6,
    const float* __restrict__ c7) {
  int gid = blockIdx.x * 256 + threadIdx.x;
  if (gid >= BATCH * NPOS) return;
  int b = gid / NPOS, n = gid - b * NPOS;
  const float* cls; int off, hw;
  if (n < 20480)      { cls = c3; off = 0;     hw = 20480; }
  else if (n < 25600) { cls = c4; off = 20480; hw = 5120;  }
  else if (n < 26880) { cls = c5; off = 25600; hw = 1280;  }
  else if (n < 27200) { cls = c6; off = 26880; hw = 320;   }
  else                { cls = c7; off = 27200; hw = 80;    }
  int local = n - off;
  const float* p = cls + (size_t)b * NCH * hw + local;
  float best = p[0]; int kind = 0;
  for (int c = 1; c < NCH; ++c) {
    float v = p[(size_t)c * hw];
    if (v > best) { best = v; kind = c; }
  }
  // correctly-rounded f32 sigmoid composition: exp in double -> f32, then IEEE add/div
  float e = (float)exp(-(double)best);
  float s = 1.0f / (1.0f + e);
  // distinct descending-sort key: (score bits, then smaller index first)
  g_key[gid] = ((u64)__float_as_uint(s) << 32) | (u32)(NPOS - n);
  g_kind[gid] = (unsigned char)kind;
}

// ---------------- K2: per-batch exact top-1000 (radix select) + sort + box decode ----------------
__global__ __launch_bounds__(1024) void k2_select(
    const float* __restrict__ r3, const float* __restrict__ r4,
    const float* __restrict__ r5, const float* __restrict__ r6,
    const float* __restrict__ r7, float* __restrict__ out) {
  int b = blockIdx.x;
  int tid = threadIdx.x;
  const u64* keys = g_key + (size_t)b * NPOS;
  __shared__ u32 hist[256];
  __shared__ u64 sh_pref;
  __shared__ int sh_target;
  __shared__ int sh_cnt;
  __shared__ u64 sk[1024];
  if (tid == 0) { sh_pref = 0; sh_target = NTOP; sh_cnt = 0; }

  // MSB-first radix select: after 8 passes sh_pref == key of rank-1000 (keys distinct)
  for (int pass = 0; pass < 8; ++pass) {
    int shift = 56 - 8 * pass;
    if (tid < 256) hist[tid] = 0;
    __syncthreads();
    u64 pref = sh_pref;
    for (int n = tid; n < NPOS; n += 1024) {
      u64 key = keys[n];
      if (pass == 0 || (key >> (shift + 8)) == pref)
        atomicAdd(&hist[(u32)(key >> shift) & 255u], 1u);
    }
    __syncthreads();
    if (tid == 0) {
      u32 target = (u32)sh_target, cnt = 0;
      int d;
      for (d = 255; d > 0; --d) {       // exits with d==0 if bin 0 is the one
        if (cnt + hist[d] >= target) break;
        cnt += hist[d];
      }
      sh_target = (int)(target - cnt);
      sh_pref = (pref << 8) | (u32)d;
    }
    __syncthreads();
  }
  u64 T = sh_pref;

  // compact the exactly-NTOP keys >= T
  sk[tid] = 0;
  __syncthreads();
  for (int n = tid; n < NPOS; n += 1024) {
    u64 key = keys[n];
    if (key >= T) { int p = atomicAdd(&sh_cnt, 1); sk[p] = key; }
  }
  __syncthreads();

  // bitonic sort 1024 keys, descending (pads are 0, sink to the end)
  for (int k = 2; k <= 1024; k <<= 1) {
    for (int j = k >> 1; j > 0; j >>= 1) {
      int ixj = tid ^ j;
      if (ixj > tid) {
        u64 a = sk[tid], c = sk[ixj];
        bool up = (tid & k) == 0;
        bool sw = up ? (a < c) : (a > c);
        if (sw) { sk[tid] = c; sk[ixj] = a; }
      }
      __syncthreads();
    }
  }

  // decode winners: box via exp(reg) gather; write out cols 0..5
  if (tid < NTOP) {
    u64 key = sk[tid];
    u32 n = (u32)NPOS - (u32)(key & 0xFFFFFFFFu);
    float s = __uint_as_float((u32)(key >> 32));
    const float* reg; int off, hw, lvl;
    if (n < 20480)      { reg = r3; off = 0;     hw = 20480; lvl = 0; }
    else if (n < 25600) { reg = r4; off = 20480; hw = 5120;  lvl = 1; }
    else if (n < 26880) { reg = r5; off = 25600; hw = 1280;  lvl = 2; }
    else if (n < 27200) { reg = r6; off = 26880; hw = 320;   lvl = 3; }
    else                { reg = r7; off = 27200; hw = 80;    lvl = 4; }
    int local = (int)n - off;
    int W = 160 >> lvl;
    int h = local / W, w = local - h * W;
    float stride = (float)(8 << lvl);
    const float* rp = reg + (size_t)b * 4 * hw + local;
    float e0 = expf(rp[0]);
    float e1 = expf(rp[(size_t)hw]);
    float e2 = expf(rp[(size_t)2 * hw]);
    float e3 = expf(rp[(size_t)3 * hw]);
    float cx = (w + 0.5f) * stride, cy = (h + 0.5f) * stride;
    float x1 = cx - e0, y1 = cy - e1, x2 = cx + e2, y2 = cy + e3;
    int ok = b * NTOP + tid;
    g_box[ok] = make_float4(x1, y1, x2, y2);
    g_score[ok] = s;
    float* o = out + (size_t)ok * 7;
    o[0] = x1; o[1] = y1; o[2] = x2; o[3] = y2;
    o[4] = (float)g_kind[(size_t)b * NPOS + n];
    o[5] = s;
  }
}

// ---------------- K3: suppression bitmask matrix (iou>0.5 & j>i) ----------------
__global__ __launch_bounds__(256) void k3_mask() {
  int gid = blockIdx.x * 256 + threadIdx.x;
  if (gid >= BATCH * NTOP * KW) return;
  int t = gid & (KW - 1);
  int rest = gid >> 4;      // KW == 16
  int i = rest % NTOP;
  int b = rest / NTOP;
  u64 word = 0;
  int j0 = t * 64;
  if (j0 + 63 > i) {
    const float4* boxes = g_box + b * NTOP;
    float4 bi = boxes[i];
    float aarea = fmaxf(bi.z - bi.x, 0.f) * fmaxf(bi.w - bi.y, 0.f);
    int jend = (j0 + 64 < NTOP) ? j0 + 64 : NTOP;
    for (int j = (j0 > i + 1 ? j0 : i + 1); j < jend; ++j) {
      float4 bj = boxes[j];
      float barea = fmaxf(bj.z - bj.x, 0.f) * fmaxf(bj.w - bj.y, 0.f);
      float ix1 = fmaxf(bi.x, bj.x), iy1 = fmaxf(bi.y, bj.y);
      float ix2 = fminf(bi.z, bj.z), iy2 = fminf(bi.w, bj.w);
      float inter = fmaxf(ix2 - ix1, 0.f) * fmaxf(iy2 - iy1, 0.f);
      // iou > 0.5  <=>  2*inter > union
      if (inter + inter > aarea + barea - inter + 1e-9f)
        word |= 1ull << (j - j0);
    }
  }
  g_mask[gid] = word;
}

// ---------------- K4: sequential greedy reduce, one wave per batch ----------------
__global__ __launch_bounds__(64) void k4_nms(float* __restrict__ out) {
  int b = blockIdx.x;
  int lane = threadIdx.x;
  int colt = lane & 15;
  int g = lane >> 4;
  u64 remv = 0;  // lanes 0..15: accumulated suppression word for column `lane`
  const u64* mask = g_mask + (size_t)b * NTOP * KW;
  for (int w = 0; w < KW; ++w) {
    // wave cooperatively holds all 64 rows x 16 cols of this word-block in registers:
    // lane (g*16+t) holds rows g*16+r (r=0..15) of column t
    u64 m[16];
#pragma unroll
    for (int r = 0; r < 16; ++r) {
      int i = w * 64 + g * 16 + r;
      m[r] = (i < NTOP) ? mask[(size_t)i * KW + colt] : 0ull;
    }
    int k = w * 64 + lane;
    float s = (k < NTOP) ? g_score[b * NTOP + k] : 0.f;
    u64 keep0 = __ballot(k < NTOP && s > 0.05f);
    u64 cur = keep0 & ~__shfl(remv, w);
    u64 rem = cur;  // uniform across lanes
#pragma unroll
    for (int g2 = 0; g2 < 4; ++g2) {
#pragma unroll
      for (int r2 = 0; r2 < 16; ++r2) {
        int bpos = g2 * 16 + r2;
        if ((rem >> bpos) & 1ull) {      // wave-uniform branch
          u64 v = __shfl(m[r2], g2 * 16 + colt);  // lane t<16 gets mask[i][t]
          u64 sw = __shfl(v, w);                  // mask[i][w] broadcast
          rem &= ~sw;
          cur &= ~sw;
          if (lane < 16) remv |= v;
        }
      }
    }
    if (k < NTOP) out[(size_t)(b * NTOP + k) * 7 + 6] = (float)((cur >> lane) & 1ull);
  }
}

extern "C" void kernel_launch(void* const* d_in, const int* in_sizes, int n_in,
                              void* d_out, int out_size, void* d_ws, size_t ws_size,
                              hipStream_t stream) {
  const float* c3 = (const float*)d_in[0];
  const float* r3 = (const float*)d_in[2];
  const float* c4 = (const float*)d_in[3];
  const float* r4 = (const float*)d_in[5];
  const float* c5 = (const float*)d_in[6];
  const float* r5 = (const float*)d_in[8];
  const float* c6 = (const float*)d_in[9];
  const float* r6 = (const float*)d_in[11];
  const float* c7 = (const float*)d_in[12];
  const float* r7 = (const float*)d_in[14];
  float* out = (float*)d_out;

  int total = BATCH * NPOS;
  hipLaunchKernelGGL(k1_score, dim3((total + 255) / 256), dim3(256), 0, stream,
                     c3, c4, c5, c6, c7);
  hipLaunchKernelGGL(k2_select, dim3(BATCH), dim3(1024), 0, stream,
                     r3, r4, r5, r6, r7, out);
  int mtotal = BATCH * NTOP * KW;
  hipLaunchKernelGGL(k3_mask, dim3((mtotal + 255) / 256), dim3(256), 0, stream);
  hipLaunchKernelGGL(k4_nms, dim3(BATCH), dim3(64), 0, stream, out);
}

// Round 3
// 249.845 us; speedup vs baseline: 1.1070x; 1.1070x over previous
//
#include <hip/hip_runtime.h>
#include <math.h>

#define BATCH 16
#define NCH 20
#define NPOS 27280
#define NTOP 1000
#define KW 16  // ceil(1024/64) words of suppression bits
#define NPT 27 // keys per thread in k2 (ceil(27280/1024))

typedef unsigned long long u64;
typedef unsigned int u32;

// Static device scratch. All fully rewritten every call.
__device__ u64 g_key[BATCH * NPOS];                 // 3.5 MB  (48-bit keys)
__device__ unsigned char g_kind[BATCH * NPOS];      // 0.44 MB
__device__ float4 g_box[BATCH * NTOP];              // 0.26 MB
__device__ float g_score[BATCH * NTOP];             // 64 KB
__device__ u64 g_mask[BATCH * NTOP * KW];           // 2 MB

// ---------------- K1: per-position score (sigmoid of max logit) + argmax, x4 vectorized ----------------
__global__ __launch_bounds__(256) void k1_score(
    const float* __restrict__ c3, const float* __restrict__ c4,
    const float* __restrict__ c5, const float* __restrict__ c6,
    const float* __restrict__ c7) {
  int gid = blockIdx.x * 256 + threadIdx.x;
  if (gid >= BATCH * (NPOS / 4)) return;
  int b = gid / (NPOS / 4);
  int n0 = (gid - b * (NPOS / 4)) * 4;
  const float* cls; int off, hw;
  if (n0 < 20480)      { cls = c3; off = 0;     hw = 20480; }
  else if (n0 < 25600) { cls = c4; off = 20480; hw = 5120;  }
  else if (n0 < 26880) { cls = c5; off = 25600; hw = 1280;  }
  else if (n0 < 27200) { cls = c6; off = 26880; hw = 320;   }
  else                 { cls = c7; off = 27200; hw = 80;    }
  int local = n0 - off;
  const float4* p = (const float4*)(cls + (size_t)b * NCH * hw + local);
  int s4 = hw >> 2;
  float4 best = p[0];
  int k0 = 0, k1 = 0, k2 = 0, k3 = 0;
  for (int c = 1; c < NCH; ++c) {
    float4 v = p[(size_t)c * s4];
    if (v.x > best.x) { best.x = v.x; k0 = c; }
    if (v.y > best.y) { best.y = v.y; k1 = c; }
    if (v.z > best.z) { best.z = v.z; k2 = c; }
    if (v.w > best.w) { best.w = v.w; k3 = c; }
  }
  // correctly-rounded f32 sigmoid composition (matches reference bit-exactly)
  u64 key[4];
  float bb[4] = {best.x, best.y, best.z, best.w};
#pragma unroll
  for (int i = 0; i < 4; ++i) {
    float e = (float)exp(-(double)bb[i]);
    float s = 1.0f / (1.0f + e);
    key[i] = ((u64)__float_as_uint(s) << 15) | (u32)(NPOS - (n0 + i));
  }
  u64* kp = &g_key[(size_t)b * NPOS + n0];
  ((ulonglong2*)kp)[0] = make_ulonglong2(key[0], key[1]);
  ((ulonglong2*)kp)[1] = make_ulonglong2(key[2], key[3]);
  u32 kind4 = (u32)k0 | ((u32)k1 << 8) | ((u32)k2 << 16) | ((u32)k3 << 24);
  *(u32*)&g_kind[(size_t)b * NPOS + n0] = kind4;
}

// ---------------- K2: per-batch exact top-1000 (register radix select) + sort + box decode ----------------
__global__ __launch_bounds__(1024) void k2_select(
    const float* __restrict__ r3, const float* __restrict__ r4,
    const float* __restrict__ r5, const float* __restrict__ r6,
    const float* __restrict__ r7, float* __restrict__ out) {
  int b = blockIdx.x;
  int tid = threadIdx.x;
  int lane = tid & 63;
  u64 lmask_lt = (1ull << lane) - 1;
  const u64* keys = g_key + (size_t)b * NPOS;

  __shared__ u32 hist[4096];
  __shared__ u64 sh_pref;
  __shared__ u32 sh_target;
  __shared__ int sh_cnt;
  __shared__ u64 sk[1024];

  // load all keys for this batch into registers (27/thread)
  u64 kreg[NPT];
#pragma unroll
  for (int i = 0; i < NPT; ++i) {
    int n = tid + i * 1024;
    kreg[i] = (n < NPOS) ? keys[n] : 0ull;
  }
  if (tid == 0) { sh_pref = 0; sh_target = NTOP; sh_cnt = 0; }

  // 4 passes x 12-bit digits over the 48-bit key
  for (int pass = 0; pass < 4; ++pass) {
    int shift = 36 - 12 * pass;
    for (int i = tid; i < 4096; i += 1024) hist[i] = 0;
    __syncthreads();
    u64 pref = sh_pref;
    u32 target = sh_target;
#pragma unroll
    for (int i = 0; i < NPT; ++i) {
      int n = tid + i * 1024;
      u64 key = kreg[i];
      bool active = (n < NPOS) && ((key >> (shift + 12)) == pref);
      u32 digit = (u32)(key >> shift) & 0xFFFu;
      // wave-aggregated histogram add (skew-immune)
      u64 exec = __ballot(active);
      while (exec) {
        int leader = __ffsll(exec) - 1;
        u32 d = __shfl(digit, leader);
        u64 mset = __ballot(active && digit == d);
        if (lane == leader) atomicAdd(&hist[d], (u32)__popcll(mset));
        exec &= ~mset;
      }
    }
    __syncthreads();
    // two-level 64x64 suffix scan by wave 0
    if (tid < 64) {
      u32 csum = 0;
      for (int i = 0; i < 64; ++i) csum += hist[tid * 64 + i];
      u32 s = csum;
      for (int off = 1; off < 64; off <<= 1) {
        u32 v = __shfl_down(s, off);
        if (lane + off < 64) s += v;
      }
      u32 cg = s - csum;  // keys in higher chunks
      bool hit = (cg < target) && (target <= s);
      u64 bal = __ballot(hit);
      int Ls = __ffsll(bal) - 1;
      u32 t2 = target - __shfl(cg, Ls);
      u32 h = hist[Ls * 64 + lane];
      u32 s2 = h;
      for (int off = 1; off < 64; off <<= 1) {
        u32 v = __shfl_down(s2, off);
        if (lane + off < 64) s2 += v;
      }
      u32 cg2 = s2 - h;
      bool hit2 = (cg2 < t2) && (t2 <= s2);
      u64 bal2 = __ballot(hit2);
      int dl = __ffsll(bal2) - 1;
      if (lane == dl) {
        sh_pref = (sh_pref << 12) | (u32)(Ls * 64 + dl);
        sh_target = t2 - cg2;
      }
    }
    __syncthreads();
  }
  u64 T = sh_pref;  // exact rank-1000 key (keys distinct)

  // compact the exactly-NTOP keys >= T (wave-aggregated counter)
  sk[tid] = 0;
  __syncthreads();
#pragma unroll
  for (int i = 0; i < NPT; ++i) {
    int n = tid + i * 1024;
    bool keep = (n < NPOS) && (kreg[i] >= T);
    u64 mset = __ballot(keep);
    if (mset) {
      int leader = __ffsll(mset) - 1;
      u32 base = 0;
      if (lane == leader) base = (u32)atomicAdd(&sh_cnt, (int)__popcll(mset));
      base = __shfl(base, leader);
      if (keep) sk[base + __popcll(mset & lmask_lt)] = kreg[i];
    }
  }
  __syncthreads();

  // bitonic sort 1024 keys, descending (pads are 0, sink to the end)
  for (int k = 2; k <= 1024; k <<= 1) {
    for (int j = k >> 1; j > 0; j >>= 1) {
      int ixj = tid ^ j;
      if (ixj > tid) {
        u64 a = sk[tid], c = sk[ixj];
        bool up = (tid & k) == 0;
        bool sw = up ? (a < c) : (a > c);
        if (sw) { sk[tid] = c; sk[ixj] = a; }
      }
      __syncthreads();
    }
  }

  // decode winners: box via exp(reg) gather; write out cols 0..5
  if (tid < NTOP) {
    u64 key = sk[tid];
    u32 n = (u32)NPOS - (u32)(key & 0x7FFFu);
    float s = __uint_as_float((u32)(key >> 15));
    const float* reg; int off, hw, lvl;
    if (n < 20480)      { reg = r3; off = 0;     hw = 20480; lvl = 0; }
    else if (n < 25600) { reg = r4; off = 20480; hw = 5120;  lvl = 1; }
    else if (n < 26880) { reg = r5; off = 25600; hw = 1280;  lvl = 2; }
    else if (n < 27200) { reg = r6; off = 26880; hw = 320;   lvl = 3; }
    else                { reg = r7; off = 27200; hw = 80;    lvl = 4; }
    int local = (int)n - off;
    int W = 160 >> lvl;
    int h = local / W, w = local - h * W;
    float stride = (float)(8 << lvl);
    const float* rp = reg + (size_t)b * 4 * hw + local;
    float e0 = expf(rp[0]);
    float e1 = expf(rp[(size_t)hw]);
    float e2 = expf(rp[(size_t)2 * hw]);
    float e3 = expf(rp[(size_t)3 * hw]);
    float cx = (w + 0.5f) * stride, cy = (h + 0.5f) * stride;
    float x1 = cx - e0, y1 = cy - e1, x2 = cx + e2, y2 = cy + e3;
    int ok = b * NTOP + tid;
    g_box[ok] = make_float4(x1, y1, x2, y2);
    g_score[ok] = s;
    float* o = out + (size_t)ok * 7;
    o[0] = x1; o[1] = y1; o[2] = x2; o[3] = y2;
    o[4] = (float)g_kind[(size_t)b * NPOS + n];
    o[5] = s;
  }
}

// ---------------- K3: suppression bitmask matrix (iou>0.5 & j>i) ----------------
__global__ __launch_bounds__(256) void k3_mask() {
  int gid = blockIdx.x * 256 + threadIdx.x;
  if (gid >= BATCH * NTOP * KW) return;
  int t = gid & (KW - 1);
  int rest = gid >> 4;      // KW == 16
  int i = rest % NTOP;
  int b = rest / NTOP;
  u64 word = 0;
  int j0 = t * 64;
  if (j0 + 63 > i) {
    const float4* boxes = g_box + b * NTOP;
    float4 bi = boxes[i];
    float aarea = fmaxf(bi.z - bi.x, 0.f) * fmaxf(bi.w - bi.y, 0.f);
    int jend = (j0 + 64 < NTOP) ? j0 + 64 : NTOP;
    for (int j = (j0 > i + 1 ? j0 : i + 1); j < jend; ++j) {
      float4 bj = boxes[j];
      float barea = fmaxf(bj.z - bj.x, 0.f) * fmaxf(bj.w - bj.y, 0.f);
      float ix1 = fmaxf(bi.x, bj.x), iy1 = fmaxf(bi.y, bj.y);
      float ix2 = fminf(bi.z, bj.z), iy2 = fminf(bi.w, bj.w);
      float inter = fmaxf(ix2 - ix1, 0.f) * fmaxf(iy2 - iy1, 0.f);
      if (inter + inter > aarea + barea - inter + 1e-9f)
        word |= 1ull << (j - j0);
    }
  }
  g_mask[gid] = word;
}

// ---------------- K4: sequential greedy reduce, one wave per batch ----------------
__global__ __launch_bounds__(64) void k4_nms(float* __restrict__ out) {
  int b = blockIdx.x;
  int lane = threadIdx.x;
  int colt = lane & 15;
  int g = lane >> 4;
  u64 remv = 0;  // lanes 0..15: accumulated suppression word for column `lane`
  const u64* mask = g_mask + (size_t)b * NTOP * KW;
  for (int w = 0; w < KW; ++w) {
    u64 m[16];
#pragma unroll
    for (int r = 0; r < 16; ++r) {
      int i = w * 64 + g * 16 + r;
      m[r] = (i < NTOP) ? mask[(size_t)i * KW + colt] : 0ull;
    }
    int k = w * 64 + lane;
    float s = (k < NTOP) ? g_score[b * NTOP + k] : 0.f;
    u64 keep0 = __ballot(k < NTOP && s > 0.05f);
    u64 cur = keep0 & ~__shfl(remv, w);
    u64 rem = cur;  // uniform across lanes
#pragma unroll
    for (int g2 = 0; g2 < 4; ++g2) {
#pragma unroll
      for (int r2 = 0; r2 < 16; ++r2) {
        int bpos = g2 * 16 + r2;
        if ((rem >> bpos) & 1ull) {      // wave-uniform branch
          u64 v = __shfl(m[r2], g2 * 16 + colt);  // lane t<16 gets mask[i][t]
          u64 sw = __shfl(v, w);                  // mask[i][w] broadcast
          rem &= ~sw;
          cur &= ~sw;
          if (lane < 16) remv |= v;
        }
      }
    }
    if (k < NTOP) out[(size_t)(b * NTOP + k) * 7 + 6] = (float)((cur >> lane) & 1ull);
  }
}

extern "C" void kernel_launch(void* const* d_in, const int* in_sizes, int n_in,
                              void* d_out, int out_size, void* d_ws, size_t ws_size,
                              hipStream_t stream) {
  const float* c3 = (const float*)d_in[0];
  const float* r3 = (const float*)d_in[2];
  const float* c4 = (const float*)d_in[3];
  const float* r4 = (const float*)d_in[5];
  const float* c5 = (const float*)d_in[6];
  const float* r5 = (const float*)d_in[8];
  const float* c6 = (const float*)d_in[9];
  const float* r6 = (const float*)d_in[11];
  const float* c7 = (const float*)d_in[12];
  const float* r7 = (const float*)d_in[14];
  float* out = (float*)d_out;

  int total4 = BATCH * (NPOS / 4);
  hipLaunchKernelGGL(k1_score, dim3((total4 + 255) / 256), dim3(256), 0, stream,
                     c3, c4, c5, c6, c7);
  hipLaunchKernelGGL(k2_select, dim3(BATCH), dim3(1024), 0, stream,
                     r3, r4, r5, r6, r7, out);
  int mtotal = BATCH * NTOP * KW;
  hipLaunchKernelGGL(k3_mask, dim3((mtotal + 255) / 256), dim3(256), 0, stream);
  hipLaunchKernelGGL(k4_nms, dim3(BATCH), dim3(64), 0, stream, out);
}

// Round 4
// 249.169 us; speedup vs baseline: 1.1100x; 1.0027x over previous
//
#include <hip/hip_runtime.h>
#include <math.h>

#define BATCH 16
#define NCH 20
#define NPOS 27280
#define NTOP 1000
#define KW 16  // ceil(1024/64) words of suppression bits
#define NPT 27 // keys per thread in k2 (ceil(27280/1024))

typedef unsigned long long u64;
typedef unsigned int u32;

// Static device scratch. All fully rewritten every call.
__device__ __align__(16) u64 g_key[BATCH * NPOS]; // 3.5 MB (47-bit keys)
__device__ unsigned char g_kind[BATCH * NPOS];    // 0.44 MB
__device__ u64 g_mask[BATCH * NTOP * KW];         // 2 MB

// ---------------- K1: per-position score (sigmoid of max logit) + argmax, x4 vectorized ----------------
__global__ __launch_bounds__(256) void k1_score(
    const float* __restrict__ c3, const float* __restrict__ c4,
    const float* __restrict__ c5, const float* __restrict__ c6,
    const float* __restrict__ c7) {
  int gid = blockIdx.x * 256 + threadIdx.x;
  if (gid >= BATCH * (NPOS / 4)) return;
  int b = gid / (NPOS / 4);
  int n0 = (gid - b * (NPOS / 4)) * 4;
  const float* cls; int off, hw;
  if (n0 < 20480)      { cls = c3; off = 0;     hw = 20480; }
  else if (n0 < 25600) { cls = c4; off = 20480; hw = 5120;  }
  else if (n0 < 26880) { cls = c5; off = 25600; hw = 1280;  }
  else if (n0 < 27200) { cls = c6; off = 26880; hw = 320;   }
  else                 { cls = c7; off = 27200; hw = 80;    }
  int local = n0 - off;
  const float4* p = (const float4*)(cls + (size_t)b * NCH * hw + local);
  int s4 = hw >> 2;
  float4 best = p[0];
  int k0 = 0, k1 = 0, k2 = 0, k3 = 0;
  for (int c = 1; c < NCH; ++c) {
    float4 v = p[(size_t)c * s4];
    if (v.x > best.x) { best.x = v.x; k0 = c; }
    if (v.y > best.y) { best.y = v.y; k1 = c; }
    if (v.z > best.z) { best.z = v.z; k2 = c; }
    if (v.w > best.w) { best.w = v.w; k3 = c; }
  }
  // correctly-rounded f32 sigmoid composition (matches reference bit-exactly)
  u64 key[4];
  float bb[4] = {best.x, best.y, best.z, best.w};
#pragma unroll
  for (int i = 0; i < 4; ++i) {
    float e = (float)exp(-(double)bb[i]);
    float s = 1.0f / (1.0f + e);
    key[i] = ((u64)__float_as_uint(s) << 15) | (u32)(NPOS - (n0 + i));
  }
  u64* kp = &g_key[(size_t)b * NPOS + n0];
  ((ulonglong2*)kp)[0] = make_ulonglong2(key[0], key[1]);
  ((ulonglong2*)kp)[1] = make_ulonglong2(key[2], key[3]);
  u32 kind4 = (u32)k0 | ((u32)k1 << 8) | ((u32)k2 << 16) | ((u32)k3 << 24);
  *(u32*)&g_kind[(size_t)b * NPOS + n0] = kind4;
}

// ---------------- K2: top-1000 select + rank + decode + NMS mask + greedy reduce (one block/batch) ----------------
__global__ __launch_bounds__(1024) void k2_fused(
    const float* __restrict__ r3, const float* __restrict__ r4,
    const float* __restrict__ r5, const float* __restrict__ r6,
    const float* __restrict__ r7, float* __restrict__ out) {
  int b = blockIdx.x;
  int tid = threadIdx.x;
  int lane = tid & 63;
  u64 lmask_lt = (1ull << lane) - 1;
  const u64* keys = g_key + (size_t)b * NPOS;

  __shared__ u32 hist[256];
  __shared__ u64 sh_pref;
  __shared__ u32 sh_target;
  __shared__ int sh_cnt;
  __shared__ u64 sk[1024];
  __shared__ float4 shbox[NTOP];
  __shared__ float shsc[NTOP];

  // load all keys for this batch into registers (27/thread)
  u64 kreg[NPT];
#pragma unroll
  for (int i = 0; i < NPT; ++i) {
    int n = tid + i * 1024;
    kreg[i] = (n < NPOS) ? keys[n] : 0ull;
  }
  if (tid == 0) { sh_pref = 0; sh_target = NTOP; sh_cnt = 0; }

  // 6 passes x 8-bit digits over the 48-bit key.
  // pass 0: wave-aggregated adds (digit = sign+exp bits -> ~2-4 distinct, heavy skew)
  // passes 1-5: plain LDS atomics (diverse digits -> collisions rare)
  for (int pass = 0; pass < 6; ++pass) {
    int shift = 40 - 8 * pass;
    if (tid < 256) hist[tid] = 0;
    __syncthreads();
    u64 pref = sh_pref;
    u32 target = sh_target;
    if (pass == 0) {
#pragma unroll
      for (int i = 0; i < NPT; ++i) {
        int n = tid + i * 1024;
        bool active = (n < NPOS);
        u32 digit = (u32)(kreg[i] >> 40) & 255u;
        u64 exec = __ballot(active);
        while (exec) {
          int leader = __ffsll(exec) - 1;
          u32 d = __shfl(digit, leader);
          u64 mset = __ballot(active && digit == d);
          if (lane == leader) atomicAdd(&hist[d], (u32)__popcll(mset));
          exec &= ~mset;
        }
      }
    } else {
#pragma unroll
      for (int i = 0; i < NPT; ++i) {
        int n = tid + i * 1024;
        if (n < NPOS && (kreg[i] >> (shift + 8)) == pref)
          atomicAdd(&hist[(u32)(kreg[i] >> shift) & 255u], 1u);
      }
    }
    __syncthreads();
    // scan by wave 0: 64 lanes x 4 bins each, rotated reads (bank-conflict-free)
    if (tid < 64) {
      int t = tid;
      u32 csum = 0;
#pragma unroll
      for (int i = 0; i < 4; ++i) csum += hist[4 * t + ((i + t) & 3)];
      u32 s = csum;
#pragma unroll
      for (int off = 1; off < 64; off <<= 1) {
        u32 v = __shfl_down(s, off);
        if (t + off < 64) s += v;
      }
      u32 cg = s - csum;  // keys in strictly-higher chunks
      bool hit = (cg < target) && (target <= s);
      u64 bal = __ballot(hit);
      int L = __ffsll(bal) - 1;
      if (t == L) {
        u32 cnt = cg;
        for (int d = 3; d >= 0; --d) {
          u32 h = hist[4 * t + d];
          if (cnt + h >= target) {
            sh_pref = (pref << 8) | (u32)(4 * t + d);
            sh_target = target - cnt;
            break;
          }
          cnt += h;
        }
      }
    }
    __syncthreads();
  }
  u64 T = sh_pref;  // exact rank-1000 key (keys distinct)

  // compact the exactly-NTOP keys >= T (wave-aggregated counter), unordered
#pragma unroll
  for (int i = 0; i < NPT; ++i) {
    int n = tid + i * 1024;
    bool keep = (n < NPOS) && (kreg[i] >= T);
    u64 mset = __ballot(keep);
    if (mset) {
      int leader = __ffsll(mset) - 1;
      u32 base = 0;
      if (lane == leader) base = (u32)atomicAdd(&sh_cnt, (int)__popcll(mset));
      base = __shfl(base, leader);
      if (keep) sk[base + __popcll(mset & lmask_lt)] = kreg[i];
    }
  }
  __syncthreads();

  // rank by counting (keys distinct -> ranks are a permutation), then decode
  if (tid < NTOP) {
    u64 myk = sk[tid];
    int rank = 0;
    for (int j = 0; j < NTOP; j += 4) {  // uniform LDS reads -> broadcast
      rank += (int)(sk[j] > myk) + (int)(sk[j + 1] > myk) +
              (int)(sk[j + 2] > myk) + (int)(sk[j + 3] > myk);
    }
    u32 n = (u32)NPOS - (u32)(myk & 0x7FFFu);
    float s = __uint_as_float((u32)(myk >> 15));
    const float* reg; int off, hw, lvl;
    if (n < 20480)      { reg = r3; off = 0;     hw = 20480; lvl = 0; }
    else if (n < 25600) { reg = r4; off = 20480; hw = 5120;  lvl = 1; }
    else if (n < 26880) { reg = r5; off = 25600; hw = 1280;  lvl = 2; }
    else if (n < 27200) { reg = r6; off = 26880; hw = 320;   lvl = 3; }
    else                { reg = r7; off = 27200; hw = 80;    lvl = 4; }
    int local = (int)n - off;
    int W = 160 >> lvl;
    int h = local / W, w = local - h * W;
    float stride = (float)(8 << lvl);
    const float* rp = reg + (size_t)b * 4 * hw + local;
    float e0 = expf(rp[0]);
    float e1 = expf(rp[(size_t)hw]);
    float e2 = expf(rp[(size_t)2 * hw]);
    float e3 = expf(rp[(size_t)3 * hw]);
    float cx = (w + 0.5f) * stride, cy = (h + 0.5f) * stride;
    float x1 = cx - e0, y1 = cy - e1, x2 = cx + e2, y2 = cy + e3;
    shbox[rank] = make_float4(x1, y1, x2, y2);
    shsc[rank] = s;
    float* o = out + (size_t)(b * NTOP + rank) * 7;
    o[0] = x1; o[1] = y1; o[2] = x2; o[3] = y2;
    o[4] = (float)g_kind[(size_t)b * NPOS + n];
    o[5] = s;
  }
  __syncthreads();

  // mask phase: thread i computes its row's 16 suppression words (j > i, iou > 0.5)
  if (tid < NTOP) {
    int i = tid;
    float4 bi = shbox[i];
    float aarea = fmaxf(bi.z - bi.x, 0.f) * fmaxf(bi.w - bi.y, 0.f);
    u64* mrow = g_mask + ((size_t)b * NTOP + i) * KW;
    for (int t = 0; t < KW; ++t) {
      u64 word = 0;
      int j0 = t * 64;
      int jbeg = (j0 > i + 1) ? j0 : i + 1;
      int jend = (j0 + 64 < NTOP) ? j0 + 64 : NTOP;
      for (int j = jbeg; j < jend; ++j) {
        float4 bj = shbox[j];
        float barea = fmaxf(bj.z - bj.x, 0.f) * fmaxf(bj.w - bj.y, 0.f);
        float ix1 = fmaxf(bi.x, bj.x), iy1 = fmaxf(bi.y, bj.y);
        float ix2 = fminf(bi.z, bj.z), iy2 = fminf(bi.w, bj.w);
        float inter = fmaxf(ix2 - ix1, 0.f) * fmaxf(iy2 - iy1, 0.f);
        if (inter + inter > aarea + barea - inter + 1e-9f)
          word |= 1ull << (j - j0);
      }
      mrow[t] = word;
    }
  }
  __syncthreads();

  // greedy sequential reduce on wave 0 (mask columns register-resident)
  if (tid < 64) {
    int colt = lane & 15;
    int g = lane >> 4;
    u64 remv = 0;  // lanes 0..15: accumulated suppression word for column `lane`
    const u64* mask = g_mask + (size_t)b * NTOP * KW;
    for (int w = 0; w < KW; ++w) {
      u64 m[16];
#pragma unroll
      for (int r = 0; r < 16; ++r) {
        int i = w * 64 + g * 16 + r;
        m[r] = (i < NTOP) ? mask[(size_t)i * KW + colt] : 0ull;
      }
      int k = w * 64 + lane;
      float s = (k < NTOP) ? shsc[k] : 0.f;
      u64 keep0 = __ballot(k < NTOP && s > 0.05f);
      u64 cur = keep0 & ~__shfl(remv, w);
      u64 rem = cur;  // uniform across lanes
#pragma unroll
      for (int g2 = 0; g2 < 4; ++g2) {
#pragma unroll
        for (int r2 = 0; r2 < 16; ++r2) {
          int bpos = g2 * 16 + r2;
          if ((rem >> bpos) & 1ull) {      // wave-uniform branch
            u64 v = __shfl(m[r2], g2 * 16 + colt);  // lane t<16 gets mask[i][t]
            u64 sw = __shfl(v, w);                  // mask[i][w] broadcast
            rem &= ~sw;
            cur &= ~sw;
            if (lane < 16) remv |= v;
          }
        }
      }
      if (k < NTOP) out[(size_t)(b * NTOP + k) * 7 + 6] = (float)((cur >> lane) & 1ull);
    }
  }
}

extern "C" void kernel_launch(void* const* d_in, const int* in_sizes, int n_in,
                              void* d_out, int out_size, void* d_ws, size_t ws_size,
                              hipStream_t stream) {
  const float* c3 = (const float*)d_in[0];
  const float* r3 = (const float*)d_in[2];
  const float* c4 = (const float*)d_in[3];
  const float* r4 = (const float*)d_in[5];
  const float* c5 = (const float*)d_in[6];
  const float* r5 = (const float*)d_in[8];
  const float* c6 = (const float*)d_in[9];
  const float* r6 = (const float*)d_in[11];
  const float* c7 = (const float*)d_in[12];
  const float* r7 = (const float*)d_in[14];
  float* out = (float*)d_out;

  int total4 = BATCH * (NPOS / 4);
  hipLaunchKernelGGL(k1_score, dim3((total4 + 255) / 256), dim3(256), 0, stream,
                     c3, c4, c5, c6, c7);
  hipLaunchKernelGGL(k2_fused, dim3(BATCH), dim3(1024), 0, stream,
                     r3, r4, r5, r6, r7, out);
}

// Round 5
// 130.974 us; speedup vs baseline: 2.1117x; 1.9024x over previous
//
#include <hip/hip_runtime.h>
#include <math.h>

#define BATCH 16
#define NCH 20
#define NPOS 27280
#define NTOP 1000
#define KW 16       // ceil(1024/64) suppression words per row
#define NBIN 4096
#define CANDCAP 4096

typedef unsigned long long u64;
typedef unsigned int u32;

// Static device scratch. Everything is either fully rewritten or zeroed (K0) each call.
__device__ __align__(16) u64 g_key[BATCH * NPOS];   // 3.5 MB (47-bit keys)
__device__ unsigned char g_kind[BATCH * NPOS];      // 0.44 MB
__device__ u32 g_hist[BATCH * NBIN];                // zeroed by K0
__device__ u32 g_dcnt[BATCH * NBIN];                // zeroed by K0
__device__ u32 g_suf[BATCH * NBIN];
__device__ int g_thr[BATCH];
__device__ int g_ncand[BATCH];
__device__ u64 g_cand[BATCH * CANDCAP];
__device__ float4 g_box[BATCH * NTOP];
__device__ float g_score[BATCH * NTOP];
__device__ u64 g_mask[BATCH * NTOP * KW];           // fully rewritten by K4b
__device__ u64 g_anysup[BATCH * KW];                // zeroed by K0

// monotone bucketing of score bits: [0.5,1) spreads over ~4096 bins (exponent skew removed)
__device__ __forceinline__ int digit_of(u32 sb) {
  int d = ((int)sb - 0x3F000000) >> 11;
  return d < 0 ? 0 : (d > (NBIN - 1) ? (NBIN - 1) : d);
}

// ---------------- K0: zero the atomically-built arrays ----------------
__global__ __launch_bounds__(1024) void k0_zero() {
  int i = blockIdx.x * 1024 + threadIdx.x;   // grid 64*1024 = 65536
  g_hist[i] = 0;
  g_dcnt[i] = 0;
  if (i < BATCH * KW) g_anysup[i] = 0;
}

// ---------------- K1: score (bit-exact sigmoid of max logit) + argmax + key + histogram ----------------
__global__ __launch_bounds__(256) void k1_score(
    const float* __restrict__ c3, const float* __restrict__ c4,
    const float* __restrict__ c5, const float* __restrict__ c6,
    const float* __restrict__ c7) {
  int gid = blockIdx.x * 256 + threadIdx.x;
  if (gid >= BATCH * (NPOS / 4)) return;
  int b = gid / (NPOS / 4);
  int n0 = (gid - b * (NPOS / 4)) * 4;
  const float* cls; int off, hw;
  if (n0 < 20480)      { cls = c3; off = 0;     hw = 20480; }
  else if (n0 < 25600) { cls = c4; off = 20480; hw = 5120;  }
  else if (n0 < 26880) { cls = c5; off = 25600; hw = 1280;  }
  else if (n0 < 27200) { cls = c6; off = 26880; hw = 320;   }
  else                 { cls = c7; off = 27200; hw = 80;    }
  int local = n0 - off;
  const float4* p = (const float4*)(cls + (size_t)b * NCH * hw + local);
  int s4 = hw >> 2;
  float4 best = p[0];
  int k0 = 0, k1 = 0, k2 = 0, k3 = 0;
  for (int c = 1; c < NCH; ++c) {
    float4 v = p[(size_t)c * s4];
    if (v.x > best.x) { best.x = v.x; k0 = c; }
    if (v.y > best.y) { best.y = v.y; k1 = c; }
    if (v.z > best.z) { best.z = v.z; k2 = c; }
    if (v.w > best.w) { best.w = v.w; k3 = c; }
  }
  u64 key[4];
  float bb[4] = {best.x, best.y, best.z, best.w};
#pragma unroll
  for (int i = 0; i < 4; ++i) {
    float e = (float)exp(-(double)bb[i]);   // correctly-rounded composition (validated bit-exact)
    float s = 1.0f / (1.0f + e);
    u32 sb = __float_as_uint(s);
    key[i] = ((u64)sb << 15) | (u32)(NPOS - (n0 + i));
    atomicAdd(&g_hist[b * NBIN + digit_of(sb)], 1u);
  }
  u64* kp = &g_key[(size_t)b * NPOS + n0];
  ((ulonglong2*)kp)[0] = make_ulonglong2(key[0], key[1]);
  ((ulonglong2*)kp)[1] = make_ulonglong2(key[2], key[3]);
  u32 kind4 = (u32)k0 | ((u32)k1 << 8) | ((u32)k2 << 16) | ((u32)k3 << 24);
  *(u32*)&g_kind[(size_t)b * NPOS + n0] = kind4;
}

// ---------------- K2: per-batch suffix scan of histogram, find threshold bucket ----------------
__global__ __launch_bounds__(64) void k2_scan() {
  int b = blockIdx.x;
  int t = threadIdx.x;            // lane owns bins [64t, 64t+64)
  const u32* h = g_hist + b * NBIN;
  u32 csum = 0;
  for (int i = 0; i < 64; ++i) csum += h[t * 64 + i];
  u32 s = csum;                   // inclusive suffix over chunks
#pragma unroll
  for (int off = 1; off < 64; off <<= 1) {
    u32 v = __shfl_down(s, off);
    if (t + off < 64) s += v;
  }
  u32 run = s - csum;             // keys in strictly-higher chunks
  for (int i = 63; i >= 0; --i) {
    int d = t * 64 + i;
    u32 hd = h[d];
    g_suf[b * NBIN + d] = run;    // keys with digit > d
    if (run < NTOP && NTOP <= run + hd) {
      g_thr[b] = d;
      g_ncand[b] = (int)(run + hd);
    }
    run += hd;
  }
}

// ---------------- K3: compact candidates (digit >= B*) into digit-grouped slots ----------------
__global__ __launch_bounds__(256) void k3_compact() {
  int gid = blockIdx.x * 256 + threadIdx.x;   // grid exactly BATCH*NPOS
  int b = gid / NPOS;
  u64 key = g_key[gid];
  int d = digit_of((u32)(key >> 15));
  if (d >= g_thr[b]) {
    u32 arrival = atomicAdd(&g_dcnt[b * NBIN + d], 1u);
    u32 slot = g_suf[b * NBIN + d] + arrival;
    if (slot < CANDCAP) g_cand[b * CANDCAP + slot] = key;
  }
}

// ---------------- K4a: exact rank (within tiny digit group) + decode + output cols 0..5 ----------------
__global__ __launch_bounds__(1024) void k4a_rank(
    const float* __restrict__ r3, const float* __restrict__ r4,
    const float* __restrict__ r5, const float* __restrict__ r6,
    const float* __restrict__ r7, float* __restrict__ out) {
  int b = blockIdx.x;
  int tid = threadIdx.x;
  __shared__ u64 sk[CANDCAP];
  int Ncand = g_ncand[b];
  if (Ncand > CANDCAP) Ncand = CANDCAP;
  for (int j = tid; j < Ncand; j += 1024) sk[j] = g_cand[b * CANDCAP + j];
  __syncthreads();
  for (int i = tid; i < Ncand; i += 1024) {
    u64 k = sk[i];
    int d = digit_of((u32)(k >> 15));
    u32 gs = g_suf[b * NBIN + d];
    u32 ge = gs + g_hist[b * NBIN + d];
    if (ge > (u32)Ncand) ge = (u32)Ncand;
    int rank = (int)gs;
    for (u32 j = gs; j < ge; ++j) rank += (int)(sk[j] > k);
    if (rank >= NTOP) continue;
    u32 n = (u32)NPOS - (u32)(k & 0x7FFFu);
    float s = __uint_as_float((u32)(k >> 15));
    const float* reg; int off, hw, lvl;
    if (n < 20480)      { reg = r3; off = 0;     hw = 20480; lvl = 0; }
    else if (n < 25600) { reg = r4; off = 20480; hw = 5120;  lvl = 1; }
    else if (n < 26880) { reg = r5; off = 25600; hw = 1280;  lvl = 2; }
    else if (n < 27200) { reg = r6; off = 26880; hw = 320;   lvl = 3; }
    else                { reg = r7; off = 27200; hw = 80;    lvl = 4; }
    int local = (int)n - off;
    int W = 160 >> lvl;
    int hh = local / W, ww = local - hh * W;
    float stride = (float)(8 << lvl);
    const float* rp = reg + (size_t)b * 4 * hw + local;
    float e0 = expf(rp[0]);
    float e1 = expf(rp[(size_t)hw]);
    float e2 = expf(rp[(size_t)2 * hw]);
    float e3 = expf(rp[(size_t)3 * hw]);
    float cx = (ww + 0.5f) * stride, cy = (hh + 0.5f) * stride;
    float x1 = cx - e0, y1 = cy - e1, x2 = cx + e2, y2 = cy + e3;
    int ok = b * NTOP + rank;
    g_box[ok] = make_float4(x1, y1, x2, y2);
    g_score[ok] = s;
    float* o = out + (size_t)ok * 7;
    o[0] = x1; o[1] = y1; o[2] = x2; o[3] = y2;
    o[4] = (float)g_kind[(size_t)b * NPOS + n];
    o[5] = s;
  }
}

// ---------------- K4b: suppression bitmask matrix (LDS-staged, wide) + per-row sup flags ----------------
__global__ __launch_bounds__(256) void k4b_mask() {
  int b = blockIdx.y;
  int ig = blockIdx.x;            // 63 groups of 16 rows
  int tid = threadIdx.x;
  __shared__ float4 shbox[NTOP];
  __shared__ float shA[NTOP];
  const float4* boxes = g_box + b * NTOP;
  for (int j = tid; j < NTOP; j += 256) {
    float4 bj = boxes[j];
    shbox[j] = bj;
    shA[j] = fmaxf(bj.z - bj.x, 0.f) * fmaxf(bj.w - bj.y, 0.f);
  }
  __syncthreads();
  int i = ig * 16 + (tid >> 4);
  int t = tid & 15;
  if (i >= NTOP) return;
  float4 bi = shbox[i];
  float aarea = shA[i];
  u64 word = 0;
  int j0 = t * 64;
  int jbeg = (j0 > i + 1) ? j0 : i + 1;
  int jend = (j0 + 64 < NTOP) ? j0 + 64 : NTOP;
  for (int j = jbeg; j < jend; ++j) {
    float4 bj = shbox[j];
    float barea = shA[j];
    float ix1 = fmaxf(bi.x, bj.x), iy1 = fmaxf(bi.y, bj.y);
    float ix2 = fminf(bi.z, bj.z), iy2 = fminf(bi.w, bj.w);
    float inter = fmaxf(ix2 - ix1, 0.f) * fmaxf(iy2 - iy1, 0.f);
    if (inter + inter > aarea + barea - inter + 1e-9f)
      word |= 1ull << (j - j0);
  }
  g_mask[((size_t)b * NTOP + i) * KW + t] = word;
  if (word) atomicOr(&g_anysup[b * KW + (i >> 6)], 1ull << (i & 63));
}

// ---------------- K4c: greedy sequential reduce, consulting only suppressor rows ----------------
__global__ __launch_bounds__(64) void k4c_greedy(float* __restrict__ out) {
  int b = blockIdx.x;
  int lane = threadIdx.x;
  int col = lane & 15, g = lane >> 4;
  const u64* mask = g_mask + (size_t)b * NTOP * KW;
  u64 remv = 0;   // column (lane&15) accumulated suppression (consistent across g-copies)
  for (int w = 0; w < KW; ++w) {
    int k = w * 64 + lane;
    float s = (k < NTOP) ? g_score[b * NTOP + k] : 0.f;
    u64 keep0 = __ballot(k < NTOP && s > 0.05f);
    u64 cur = keep0 & ~__shfl(remv, w);
    u64 mdiag = (k < NTOP) ? mask[(size_t)k * KW + w] : 0ull;
    u64 rem = cur & g_anysup[b * KW + w];   // only rows that can suppress anyone
    u64 acc = 0;
    while (rem) {
      int i = __ffsll(rem) - 1;             // uniform
      u64 v = __shfl(mdiag, i);             // mask[w*64+i][w]
      rem &= ~(v | (1ull << i));
      cur &= ~v;
      acc |= (1ull << i);
    }
    // propagate accepted suppressors' rows into future words
    u64 upd = 0;
#pragma unroll
    for (int r = 0; r < 16; ++r) {
      int i = g * 16 + r;
      if ((acc >> i) & 1ull)
        upd |= mask[(size_t)(w * 64 + i) * KW + col];
    }
    upd |= __shfl_xor(upd, 16);
    upd |= __shfl_xor(upd, 32);
    remv |= upd;
    if (k < NTOP) out[(size_t)(b * NTOP + k) * 7 + 6] = (float)((cur >> lane) & 1ull);
  }
}

extern "C" void kernel_launch(void* const* d_in, const int* in_sizes, int n_in,
                              void* d_out, int out_size, void* d_ws, size_t ws_size,
                              hipStream_t stream) {
  const float* c3 = (const float*)d_in[0];
  const float* r3 = (const float*)d_in[2];
  const float* c4 = (const float*)d_in[3];
  const float* r4 = (const float*)d_in[5];
  const float* c5 = (const float*)d_in[6];
  const float* r5 = (const float*)d_in[8];
  const float* c6 = (const float*)d_in[9];
  const float* r6 = (const float*)d_in[11];
  const float* c7 = (const float*)d_in[12];
  const float* r7 = (const float*)d_in[14];
  float* out = (float*)d_out;

  hipLaunchKernelGGL(k0_zero, dim3(64), dim3(1024), 0, stream);
  int total4 = BATCH * (NPOS / 4);
  hipLaunchKernelGGL(k1_score, dim3((total4 + 255) / 256), dim3(256), 0, stream,
                     c3, c4, c5, c6, c7);
  hipLaunchKernelGGL(k2_scan, dim3(BATCH), dim3(64), 0, stream);
  hipLaunchKernelGGL(k3_compact, dim3(BATCH * NPOS / 256), dim3(256), 0, stream);
  hipLaunchKernelGGL(k4a_rank, dim3(BATCH), dim3(1024), 0, stream,
                     r3, r4, r5, r6, r7, out);
  hipLaunchKernelGGL(k4b_mask, dim3(63, BATCH), dim3(256), 0, stream);
  hipLaunchKernelGGL(k4c_greedy, dim3(BATCH), dim3(64), 0, stream, out);
}

// Round 6
// 95.589 us; speedup vs baseline: 2.8934x; 1.3702x over previous
//
#include <hip/hip_runtime.h>
#include <math.h>

#define BATCH 16
#define NCH 20
#define NPOS 27280
#define NTOP 1000
#define KW 16       // ceil(1024/64) suppression words per row
#define NBIN 4096
#define CANDCAP 4096

typedef unsigned long long u64;
typedef unsigned int u32;

// Static device scratch. Everything below is fully rewritten every call.
__device__ __align__(16) u64 g_key[BATCH * NPOS];   // 3.5 MB (47-bit keys)
__device__ unsigned char g_kind[BATCH * NPOS];      // 0.44 MB
__device__ float4 g_box[BATCH * NTOP];
__device__ float g_score[BATCH * NTOP];
__device__ u64 g_mask[BATCH * NTOP * KW];           // 2 MB
__device__ unsigned char g_rowsup[BATCH * NTOP];    // per-row "suppresses someone" flag

// monotone bucketing of score bits: [0.5,1) spreads over ~4096 bins (exponent skew removed)
__device__ __forceinline__ int digit_of(u32 sb) {
  int d = ((int)sb - 0x3F000000) >> 11;
  return d < 0 ? 0 : (d > (NBIN - 1) ? (NBIN - 1) : d);
}

// ---------------- K1: score (bit-exact sigmoid of max logit) + argmax + key, pure streaming ----------------
__global__ __launch_bounds__(256) void k1_score(
    const float* __restrict__ c3, const float* __restrict__ c4,
    const float* __restrict__ c5, const float* __restrict__ c6,
    const float* __restrict__ c7) {
  int gid = blockIdx.x * 256 + threadIdx.x;
  if (gid >= BATCH * (NPOS / 4)) return;
  int b = gid / (NPOS / 4);
  int n0 = (gid - b * (NPOS / 4)) * 4;
  const float* cls; int off, hw;
  if (n0 < 20480)      { cls = c3; off = 0;     hw = 20480; }
  else if (n0 < 25600) { cls = c4; off = 20480; hw = 5120;  }
  else if (n0 < 26880) { cls = c5; off = 25600; hw = 1280;  }
  else if (n0 < 27200) { cls = c6; off = 26880; hw = 320;   }
  else                 { cls = c7; off = 27200; hw = 80;    }
  int local = n0 - off;
  const float4* p = (const float4*)(cls + (size_t)b * NCH * hw + local);
  int s4 = hw >> 2;
  float4 best = p[0];
  int k0 = 0, k1 = 0, k2 = 0, k3 = 0;
  for (int c = 1; c < NCH; ++c) {
    float4 v = p[(size_t)c * s4];
    if (v.x > best.x) { best.x = v.x; k0 = c; }
    if (v.y > best.y) { best.y = v.y; k1 = c; }
    if (v.z > best.z) { best.z = v.z; k2 = c; }
    if (v.w > best.w) { best.w = v.w; k3 = c; }
  }
  u64 key[4];
  float bb[4] = {best.x, best.y, best.z, best.w};
#pragma unroll
  for (int i = 0; i < 4; ++i) {
    float e = (float)exp(-(double)bb[i]);   // correctly-rounded composition (validated bit-exact)
    float s = 1.0f / (1.0f + e);
    key[i] = ((u64)__float_as_uint(s) << 15) | (u32)(NPOS - (n0 + i));
  }
  u64* kp = &g_key[(size_t)b * NPOS + n0];
  ((ulonglong2*)kp)[0] = make_ulonglong2(key[0], key[1]);
  ((ulonglong2*)kp)[1] = make_ulonglong2(key[2], key[3]);
  u32 kind4 = (u32)k0 | ((u32)k1 << 8) | ((u32)k2 << 16) | ((u32)k3 << 24);
  *(u32*)&g_kind[(size_t)b * NPOS + n0] = kind4;
}

// ---------------- K2: per-batch hist + scan + compact + rank + decode (one block/batch, all LDS) ----------------
__global__ __launch_bounds__(1024) void k2_select(
    const float* __restrict__ r3, const float* __restrict__ r4,
    const float* __restrict__ r5, const float* __restrict__ r6,
    const float* __restrict__ r7, float* __restrict__ out) {
  int b = blockIdx.x;
  int tid = threadIdx.x;
  int lane = tid & 63, wid = tid >> 6;
  const u64* keys = g_key + (size_t)b * NPOS;

  __shared__ u32 arr[NBIN];     // counts, then arrival counters
  __shared__ u32 suf[NBIN];     // exclusive suffix: keys with digit > d
  __shared__ u64 scand[CANDCAP];
  __shared__ u32 wsum[16];
  __shared__ int sh_thr, sh_ncand;

  // zero counts
  for (int j = tid; j < NBIN; j += 1024) arr[j] = 0;
  __syncthreads();

  // pass 1: histogram (transient key registers, coalesced reads; LDS atomics, diverse digits)
  for (int i = 0; i < 27; ++i) {
    int n = tid + i * 1024;
    if (n < NPOS) atomicAdd(&arr[digit_of((u32)(keys[n] >> 15))], 1u);
  }
  __syncthreads();

  // block-wide descending suffix scan of 4096 bins (4 bins/thread)
  u32 c[4];
#pragma unroll
  for (int k = 0; k < 4; ++k) c[k] = arr[4 * tid + k];
  u32 tot = c[0] + c[1] + c[2] + c[3];
  u32 s = tot;
#pragma unroll
  for (int off = 1; off < 64; off <<= 1) {
    u32 v = __shfl_down(s, off);
    if (lane + off < 64) s += v;
  }
  if (lane == 0) wsum[wid] = s;       // wave total
  __syncthreads();
  u32 wexcl = 0;
  for (int w2 = wid + 1; w2 < 16; ++w2) wexcl += wsum[w2];
  u32 e = wexcl + (s - tot);          // keys in bins above this thread's 4
  {
    u32 e3 = e;
    u32 e2 = e3 + c[3];
    u32 e1 = e2 + c[2];
    u32 e0 = e1 + c[1];
    suf[4 * tid + 3] = e3;
    suf[4 * tid + 2] = e2;
    suf[4 * tid + 1] = e1;
    suf[4 * tid + 0] = e0;
    if (e3 < NTOP && NTOP <= e3 + c[3]) { sh_thr = 4 * tid + 3; sh_ncand = (int)(e3 + c[3]); }
    if (e2 < NTOP && NTOP <= e2 + c[2]) { sh_thr = 4 * tid + 2; sh_ncand = (int)(e2 + c[2]); }
    if (e1 < NTOP && NTOP <= e1 + c[1]) { sh_thr = 4 * tid + 1; sh_ncand = (int)(e1 + c[1]); }
    if (e0 < NTOP && NTOP <= e0 + c[0]) { sh_thr = 4 * tid + 0; sh_ncand = (int)(e0 + c[0]); }
  }
  __syncthreads();
  int thr = sh_thr;
  int Ncand = sh_ncand < CANDCAP ? sh_ncand : CANDCAP;

  // re-zero arrival counters
  for (int j = tid; j < NBIN; j += 1024) arr[j] = 0;
  __syncthreads();

  // pass 2: compact candidates (digit >= thr) into digit-grouped LDS slots
  for (int i = 0; i < 27; ++i) {
    int n = tid + i * 1024;
    if (n < NPOS) {
      u64 key = keys[n];
      int d = digit_of((u32)(key >> 15));
      if (d >= thr) {
        u32 slot = suf[d] + atomicAdd(&arr[d], 1u);
        if (slot < CANDCAP) scand[slot] = key;
      }
    }
  }
  __syncthreads();

  // rank within tiny digit group + decode + output cols 0..5
  for (int i = tid; i < Ncand; i += 1024) {
    u64 k = scand[i];
    int d = digit_of((u32)(k >> 15));
    u32 gs = suf[d];
    u32 ge = (d > 0) ? suf[d - 1] : (u32)NPOS;   // = suf[d] + count[d]
    if (ge > (u32)Ncand) ge = (u32)Ncand;
    int rank = (int)gs;
    for (u32 j = gs; j < ge; ++j) rank += (int)(scand[j] > k);
    if (rank >= NTOP) continue;
    u32 n = (u32)NPOS - (u32)(k & 0x7FFFu);
    float sc = __uint_as_float((u32)(k >> 15));
    const float* reg; int off, hw, lvl;
    if (n < 20480)      { reg = r3; off = 0;     hw = 20480; lvl = 0; }
    else if (n < 25600) { reg = r4; off = 20480; hw = 5120;  lvl = 1; }
    else if (n < 26880) { reg = r5; off = 25600; hw = 1280;  lvl = 2; }
    else if (n < 27200) { reg = r6; off = 26880; hw = 320;   lvl = 3; }
    else                { reg = r7; off = 27200; hw = 80;    lvl = 4; }
    int local = (int)n - off;
    int W = 160 >> lvl;
    int hh = local / W, ww = local - hh * W;
    float stride = (float)(8 << lvl);
    const float* rp = reg + (size_t)b * 4 * hw + local;
    float e0 = expf(rp[0]);
    float e1 = expf(rp[(size_t)hw]);
    float e2 = expf(rp[(size_t)2 * hw]);
    float e3 = expf(rp[(size_t)3 * hw]);
    float cx = (ww + 0.5f) * stride, cy = (hh + 0.5f) * stride;
    float x1 = cx - e0, y1 = cy - e1, x2 = cx + e2, y2 = cy + e3;
    int ok = b * NTOP + rank;
    g_box[ok] = make_float4(x1, y1, x2, y2);
    g_score[ok] = sc;
    float* o = out + (size_t)ok * 7;
    o[0] = x1; o[1] = y1; o[2] = x2; o[3] = y2;
    o[4] = (float)g_kind[(size_t)b * NPOS + n];
    o[5] = sc;
  }
}

// ---------------- K4b: suppression bitmask matrix (LDS-staged, wide) + per-row sup flags ----------------
__global__ __launch_bounds__(256) void k4b_mask() {
  int b = blockIdx.y;
  int ig = blockIdx.x;            // 63 groups of 16 rows
  int tid = threadIdx.x;
  __shared__ float4 shbox[NTOP];
  __shared__ float shA[NTOP];
  const float4* boxes = g_box + b * NTOP;
  for (int j = tid; j < NTOP; j += 256) {
    float4 bj = boxes[j];
    shbox[j] = bj;
    shA[j] = fmaxf(bj.z - bj.x, 0.f) * fmaxf(bj.w - bj.y, 0.f);
  }
  __syncthreads();
  int i = ig * 16 + (tid >> 4);
  int t = tid & 15;
  u64 word = 0;
  if (i < NTOP) {
    float4 bi = shbox[i];
    float aarea = shA[i];
    int j0 = t * 64;
    int jbeg = (j0 > i + 1) ? j0 : i + 1;
    int jend = (j0 + 64 < NTOP) ? j0 + 64 : NTOP;
    for (int j = jbeg; j < jend; ++j) {
      float4 bj = shbox[j];
      float barea = shA[j];
      float ix1 = fmaxf(bi.x, bj.x), iy1 = fmaxf(bi.y, bj.y);
      float ix2 = fminf(bi.z, bj.z), iy2 = fminf(bi.w, bj.w);
      float inter = fmaxf(ix2 - ix1, 0.f) * fmaxf(iy2 - iy1, 0.f);
      if (inter + inter > aarea + barea - inter + 1e-9f)
        word |= 1ull << (j - j0);
    }
    g_mask[((size_t)b * NTOP + i) * KW + t] = word;
  }
  // per-row "has any suppression bit" flag, no atomics (ballot across the 16 word-columns)
  u64 b16 = __ballot(word != 0);
  int r = (tid & 63) >> 4;        // row-group within wave
  if (t == 0 && i < NTOP)
    g_rowsup[b * NTOP + i] = (unsigned char)(((b16 >> (r * 16)) & 0xFFFFull) ? 1 : 0);
}

// ---------------- K4c: greedy sequential reduce, consulting only suppressor rows ----------------
__global__ __launch_bounds__(64) void k4c_greedy(float* __restrict__ out) {
  int b = blockIdx.x;
  int lane = threadIdx.x;
  int col = lane & 15, g = lane >> 4;
  const u64* mask = g_mask + (size_t)b * NTOP * KW;
  u64 remv = 0;   // column (lane&15) accumulated suppression (replicated across g-copies)
  for (int w = 0; w < KW; ++w) {
    int k = w * 64 + lane;
    float s = (k < NTOP) ? g_score[b * NTOP + k] : 0.f;
    unsigned char rs = (k < NTOP) ? g_rowsup[b * NTOP + k] : (unsigned char)0;
    u64 keep0 = __ballot(k < NTOP && s > 0.05f);
    u64 gate = __ballot(rs != 0);
    u64 cur = keep0 & ~__shfl(remv, w);
    u64 mdiag = (k < NTOP) ? mask[(size_t)k * KW + w] : 0ull;
    u64 rem = cur & gate;           // only rows that can suppress anyone
    u64 acc = 0;
    while (rem) {
      int i = __ffsll(rem) - 1;     // uniform: highest-score remaining suppressor
      u64 v = __shfl(mdiag, i);     // mask[w*64+i][w]
      rem &= ~(v | (1ull << i));
      cur &= ~v;
      acc |= (1ull << i);
    }
    // propagate accepted suppressors' rows into future words
    u64 upd = 0;
#pragma unroll
    for (int r = 0; r < 16; ++r) {
      int i = g * 16 + r;
      if ((acc >> i) & 1ull)
        upd |= mask[(size_t)(w * 64 + i) * KW + col];
    }
    upd |= __shfl_xor(upd, 16);
    upd |= __shfl_xor(upd, 32);
    remv |= upd;
    if (k < NTOP) out[(size_t)(b * NTOP + k) * 7 + 6] = (float)((cur >> lane) & 1ull);
  }
}

extern "C" void kernel_launch(void* const* d_in, const int* in_sizes, int n_in,
                              void* d_out, int out_size, void* d_ws, size_t ws_size,
                              hipStream_t stream) {
  const float* c3 = (const float*)d_in[0];
  const float* r3 = (const float*)d_in[2];
  const float* c4 = (const float*)d_in[3];
  const float* r4 = (const float*)d_in[5];
  const float* c5 = (const float*)d_in[6];
  const float* r5 = (const float*)d_in[8];
  const float* c6 = (const float*)d_in[9];
  const float* r6 = (const float*)d_in[11];
  const float* c7 = (const float*)d_in[12];
  const float* r7 = (const float*)d_in[14];
  float* out = (float*)d_out;

  int total4 = BATCH * (NPOS / 4);
  hipLaunchKernelGGL(k1_score, dim3((total4 + 255) / 256), dim3(256), 0, stream,
                     c3, c4, c5, c6, c7);
  hipLaunchKernelGGL(k2_select, dim3(BATCH), dim3(1024), 0, stream,
                     r3, r4, r5, r6, r7, out);
  hipLaunchKernelGGL(k4b_mask, dim3(63, BATCH), dim3(256), 0, stream);
  hipLaunchKernelGGL(k4c_greedy, dim3(BATCH), dim3(64), 0, stream, out);
}